// Round 12
// baseline (560.715 us; speedup 1.0000x reference)
//
#include <hip/hip_runtime.h>

#define SEQ    2048
#define DMODEL 1024
#define NHEAD  16
#define HDIM   64
#define NBATCH 4
#define LOG2E  1.44269504088896f

typedef __bf16 bf16x8 __attribute__((ext_vector_type(8)));
typedef float  f32x4  __attribute__((ext_vector_type(4)));
typedef unsigned short ushort8_t __attribute__((ext_vector_type(8)));
typedef unsigned short ushort4_t __attribute__((ext_vector_type(4)));

__device__ __forceinline__ unsigned short bfc(float f) {
  union { __bf16 h; unsigned short u; } v;
  v.h = (__bf16)f;
  return v.u;
}

__device__ __forceinline__ float fexp2(float x) {
#if __has_builtin(__builtin_amdgcn_exp2f)
  return __builtin_amdgcn_exp2f(x);
#else
  return exp2f(x);
#endif
}

// async global->LDS, 16B per lane; LDS dest = wave-uniform base + lane*16
__device__ __forceinline__ void glds16(const void* g, void* l) {
  __builtin_amdgcn_global_load_lds(
      (const __attribute__((address_space(1))) unsigned int*)g,
      (__attribute__((address_space(3))) unsigned int*)l, 16, 0, 0);
}

// ---------------- X fp32 -> bf16 ----------------
__global__ __launch_bounds__(256) void xconv(
    const float* __restrict__ X, unsigned short* __restrict__ Xb)
{
  const size_t i = ((size_t)blockIdx.x * 256 + threadIdx.x) * 8;
  const float4 f0 = *reinterpret_cast<const float4*>(X + i);
  const float4 f1 = *reinterpret_cast<const float4*>(X + i + 4);
  ushort8_t u;
  u[0]=bfc(f0.x); u[1]=bfc(f0.y); u[2]=bfc(f0.z); u[3]=bfc(f0.w);
  u[4]=bfc(f1.x); u[5]=bfc(f1.y); u[6]=bfc(f1.z); u[7]=bfc(f1.w);
  *reinterpret_cast<ushort8_t*>(Xb + i) = u;
}

// ---------------- W transpose: W[k][n] fp32 -> Wt[w*1024+n][k] bf16 ---------
__global__ __launch_bounds__(256) void wt_kernel(
    const float* __restrict__ W0, const float* __restrict__ W1,
    const float* __restrict__ W2, unsigned short* __restrict__ Wt)
{
  const int k0 = blockIdx.x * 64;
  const int n0 = blockIdx.y * 64;
  const int w  = blockIdx.z;
  const float* W = (w == 0) ? W0 : (w == 1) ? W1 : W2;
  const float scale = (w == 0) ? 0.125f * LOG2E : 1.0f;
  unsigned short* dst = Wt + (size_t)w * DMODEL * DMODEL;

  __shared__ __align__(16) unsigned short T[64][72];
  const int t = threadIdx.x;

  #pragma unroll
  for (int i = 0; i < 4; ++i) {
    const int slot = t + i * 256;
    const int row  = slot >> 4;
    const int c4   = (slot & 15) * 4;
    const float4 f = *reinterpret_cast<const float4*>(W + (size_t)(k0 + row) * DMODEL + n0 + c4);
    ushort4_t u;
    u.x = bfc(f.x * scale); u.y = bfc(f.y * scale);
    u.z = bfc(f.z * scale); u.w = bfc(f.w * scale);
    *reinterpret_cast<ushort4_t*>(&T[row][c4]) = u;
  }
  __syncthreads();
  #pragma unroll
  for (int i = 0; i < 2; ++i) {
    const int slot = t + i * 256;
    const int n  = slot >> 3;
    const int k8 = (slot & 7) * 8;
    ushort8_t v;
    #pragma unroll
    for (int j = 0; j < 8; ++j) v[j] = T[k8 + j][n];
    *reinterpret_cast<ushort8_t*>(dst + (size_t)(n0 + n) * DMODEL + k0 + k8) = v;
  }
}

// ---------------- fused QKV GEMM, m97 structure -----------------------------
// w==2 (V) writes TRANSPOSED directly: Vt[bh][d][ss..ss+3] (8B nt stores).
// All epilogue stores non-temporal so the 192MB output stream doesn't evict
// Wt/Xb (heavily re-read) from L2.
__global__ __launch_bounds__(256) void qkv_gemm(
    const unsigned short* __restrict__ Xb, const unsigned short* __restrict__ Wt,
    const float* __restrict__ bq, const float* __restrict__ bk, const float* __restrict__ bv,
    unsigned short* __restrict__ Qh, unsigned short* __restrict__ Kh, unsigned short* __restrict__ Vt)
{
  const int m0  = blockIdx.x * 128;
  const int n0g = blockIdx.y * 128;
  const int w   = n0g >> 10;
  const float* bias = (w == 0) ? bq : (w == 1) ? bk : bv;
  const float bscale = (w == 0) ? 0.125f * LOG2E : 1.0f;

  __shared__ __align__(16) unsigned short As[128 * 64];
  __shared__ __align__(16) unsigned short Bs[128 * 64];

  const int t = threadIdx.x;
  const int lane = t & 63;
  const int wid  = t >> 6;
  const int wm = wid >> 1, wn = wid & 1;
  const int lr = lane & 15, lg = lane >> 4;

  const f32x4 fz = {0.f, 0.f, 0.f, 0.f};
  f32x4 acc[4][4];
  #pragma unroll
  for (int i = 0; i < 4; ++i)
    #pragma unroll
    for (int j = 0; j < 4; ++j) acc[i][j] = fz;

  const int srow = t >> 3;
  const int sg   = t & 7;

  for (int k0 = 0; k0 < DMODEL; k0 += 64) {
    #pragma unroll
    for (int i = 0; i < 4; ++i) {
      const int row = i * 32 + srow;
      const int gs  = sg ^ (row & 7);
      glds16(Xb + (size_t)(m0 + row) * DMODEL + k0 + gs * 8,
             (void*)(As + row * 64 + sg * 8));
      glds16(Wt + (size_t)(n0g + row) * DMODEL + k0 + gs * 8,
             (void*)(Bs + row * 64 + sg * 8));
    }
    __syncthreads();

    #pragma unroll
    for (int ks = 0; ks < 2; ++ks) {
      bf16x8 a[4], b[4];
      #pragma unroll
      for (int mi = 0; mi < 4; ++mi) {
        const int row = wm * 64 + mi * 16 + lr;
        a[mi] = *reinterpret_cast<const bf16x8*>(As + row * 64 + ((ks * 4 + lg) ^ (row & 7)) * 8);
      }
      #pragma unroll
      for (int ni = 0; ni < 4; ++ni) {
        const int row = wn * 64 + ni * 16 + lr;
        b[ni] = *reinterpret_cast<const bf16x8*>(Bs + row * 64 + ((ks * 4 + lg) ^ (row & 7)) * 8);
      }
      #pragma unroll
      for (int mi = 0; mi < 4; ++mi)
        #pragma unroll
        for (int ni = 0; ni < 4; ++ni)
          acc[mi][ni] = __builtin_amdgcn_mfma_f32_16x16x32_bf16(a[mi], b[ni], acc[mi][ni], 0, 0, 0);
    }
    __syncthreads();
  }

  unsigned short* dst = (w == 0) ? Qh : Kh;
  #pragma unroll
  for (int mi = 0; mi < 4; ++mi) {
    #pragma unroll
    for (int ni = 0; ni < 4; ++ni) {
      const int n = (n0g & 1023) + wn * 64 + ni * 16 + lr;
      const float bn = bias[n] * bscale;
      const int h = n >> 6, d = n & 63;
      const int m = m0 + wm * 64 + mi * 16 + lg * 4;
      const int bb = m >> 11, ss = m & (SEQ - 1);
      if (w == 2) {
        ushort4_t u;
        #pragma unroll
        for (int r = 0; r < 4; ++r) u[r] = bfc(acc[mi][ni][r] + bn);
        __builtin_nontemporal_store(u, reinterpret_cast<ushort4_t*>(
            Vt + (((size_t)(bb * NHEAD + h)) * HDIM + d) * SEQ + ss));
      } else {
        #pragma unroll
        for (int r = 0; r < 4; ++r)
          __builtin_nontemporal_store(bfc(acc[mi][ni][r] + bn),
              dst + (((size_t)(bb * NHEAD + h)) * SEQ + ss + r) * HDIM + d);
      }
    }
  }
}

// ---------------- fused attention (R10, unchanged) --------------------------
// 1-D grid 2048, XCD-chunked (T1). Mask row staged to LDS (pre-scaled) so the
// pass-2 vmcnt FIFO is exactly [4 glds][4 nt stores] and the counted vmcnt(4)
// keeps the kt+1 prefetch in flight across the whole tile. probs/ctx nt.
__global__ __launch_bounds__(256) void attn_kernel(
    const unsigned short* __restrict__ Qh, const unsigned short* __restrict__ Kh,
    const unsigned short* __restrict__ Vt, const float* __restrict__ mask,
    float* __restrict__ ctx_out, float* __restrict__ probs_out)
{
  const int bid = blockIdx.x;
  const int L   = (bid & 7) * 256 + (bid >> 3);   // XCD-chunked logical id
  const int qt  = L & 31;
  const int bh  = L >> 5;          // 8 consecutive bh per XCD
  const int h   = bh & (NHEAD - 1);
  const int b   = bh >> 4;

  const int t = threadIdx.x;
  const int lane = t & 63;
  const int wid = t >> 6;
  const int lr = lane & 15, lg = lane >> 4;

  __shared__ __align__(16) unsigned short QP[64 * 64];     // Q staging, then Ps
  __shared__ __align__(16) unsigned short Ks[2][64 * 64];  // linear, XOR-swizzled
  __shared__ __align__(16) unsigned short Vs[2][64 * 64];  // [d][key] swizzled
  __shared__ __align__(16) float Msk[SEQ];                 // mask*log2e

  const size_t qkv_base = (size_t)bh * SEQ * HDIM;
  const size_t vbase    = (size_t)bh * HDIM * SEQ;

  // stage Q tile (64x64) + mask row (pre-scaled)
  {
    const int srow = t >> 3, sc8 = (t & 7) * 8;
    #pragma unroll
    for (int c = 0; c < 2; ++c) {
      const int rr = srow + c * 32;
      *reinterpret_cast<ushort8_t*>(&QP[rr * 64 + sc8]) =
        *reinterpret_cast<const ushort8_t*>(Qh + qkv_base + (size_t)(qt*64 + rr) * HDIM + sc8);
    }
    const float* maskb = mask + b * SEQ;
    #pragma unroll
    for (int i = 0; i < 2; ++i) {
      const int slot = t + i * 256;
      const float4 mv = *reinterpret_cast<const float4*>(maskb + slot * 4);
      f32x4 m4; m4[0]=mv.x*LOG2E; m4[1]=mv.y*LOG2E; m4[2]=mv.z*LOG2E; m4[3]=mv.w*LOG2E;
      *reinterpret_cast<f32x4*>(&Msk[slot * 4]) = m4;
    }
  }
  __syncthreads();

  bf16x8 qa[2];
  qa[0] = *reinterpret_cast<const bf16x8*>(&QP[(wid*16 + lr) * 64 + lg*8]);
  qa[1] = *reinterpret_cast<const bf16x8*>(&QP[(wid*16 + lr) * 64 + 32 + lg*8]);
  __syncthreads();   // all waves hold Q in regs before QP is reused as Ps

  const int krow = t >> 3;
  const int ksg  = t & 7;

  auto stageK = [&](int buf, int kt) {
    #pragma unroll
    for (int i = 0; i < 2; ++i) {
      const int row = i * 32 + krow;
      glds16(Kh + qkv_base + (size_t)(kt*64 + row) * HDIM + ((ksg ^ (row & 7)) * 8),
             (void*)(&Ks[buf][row * 64 + ksg * 8]));
    }
  };
  auto stageV = [&](int buf, int kt) {
    #pragma unroll
    for (int i = 0; i < 2; ++i) {
      const int row = i * 32 + krow;   // d
      glds16(Vt + vbase + (size_t)row * SEQ + kt*64 + ((ksg ^ (row & 7)) * 8),
             (void*)(&Vs[buf][row * 64 + ksg * 8]));
    }
  };

  const f32x4 fz = {0.f, 0.f, 0.f, 0.f};
  float l0 = 0.f, l1 = 0.f;

  // ---- pass 1: S^T = K*Q^T, per-lane exp2 sums ----
  stageK(0, 0);
  asm volatile("s_waitcnt vmcnt(0)" ::: "memory");
  __builtin_amdgcn_sched_barrier(0);
  __builtin_amdgcn_s_barrier();

  for (int kt = 0; kt < SEQ / 64; ++kt) {
    const int cur = kt & 1;
    if (kt < SEQ / 64 - 1) stageK(cur ^ 1, kt + 1);
    __builtin_amdgcn_sched_barrier(0);

    f32x4 s[4];
    #pragma unroll
    for (int ni = 0; ni < 4; ++ni) s[ni] = fz;
    __builtin_amdgcn_s_setprio(1);
    #pragma unroll
    for (int kd = 0; kd < 2; ++kd) {
      #pragma unroll
      for (int ni = 0; ni < 4; ++ni) {
        const int row = ni*16 + lr;
        const bf16x8 kb = *reinterpret_cast<const bf16x8*>(
            &Ks[cur][row * 64 + ((kd*4 + lg) ^ (lr & 7)) * 8]);
        s[ni] = __builtin_amdgcn_mfma_f32_16x16x32_bf16(kb, qa[kd], s[ni], 0, 0, 0);
      }
    }
    __builtin_amdgcn_s_setprio(0);
    #pragma unroll
    for (int ni = 0; ni < 4; ++ni) {
      const f32x4 mv = *reinterpret_cast<const f32x4*>(&Msk[kt*64 + ni*16 + lg*4]);
      l0 += fexp2(s[ni][0] + mv[0]);
      l1 += fexp2(s[ni][1] + mv[1]);
      l0 += fexp2(s[ni][2] + mv[2]);
      l1 += fexp2(s[ni][3] + mv[3]);
    }
    __builtin_amdgcn_sched_barrier(0);
    asm volatile("s_waitcnt vmcnt(0)" ::: "memory");
    __builtin_amdgcn_sched_barrier(0);
    __builtin_amdgcn_s_barrier();
  }

  float l = l0 + l1;
  l += __shfl_xor(l, 16);
  l += __shfl_xor(l, 32);
  const float inv_l = 1.0f / l;

  // ---- pass 2: recompute S^T, write probs (nt), PV (ctx^T = V^T * P^T) ----
  f32x4 cacc[4];
  #pragma unroll
  for (int nd = 0; nd < 4; ++nd) cacc[nd] = fz;

  const size_t pbase = ((size_t)bh * SEQ + qt*64) * SEQ;

  stageK(0, 0); stageV(0, 0);
  asm volatile("s_waitcnt vmcnt(0)" ::: "memory");
  __builtin_amdgcn_sched_barrier(0);
  __builtin_amdgcn_s_barrier();

  for (int kt = 0; kt < SEQ / 64; ++kt) {
    const int cur = kt & 1;
    const bool pre = (kt < SEQ / 64 - 1);
    if (pre) { stageK(cur ^ 1, kt + 1); stageV(cur ^ 1, kt + 1); }
    __builtin_amdgcn_sched_barrier(0);

    f32x4 s[4];
    #pragma unroll
    for (int ni = 0; ni < 4; ++ni) s[ni] = fz;
    __builtin_amdgcn_s_setprio(1);
    #pragma unroll
    for (int kd = 0; kd < 2; ++kd) {
      #pragma unroll
      for (int ni = 0; ni < 4; ++ni) {
        const int row = ni*16 + lr;
        const bf16x8 kb = *reinterpret_cast<const bf16x8*>(
            &Ks[cur][row * 64 + ((kd*4 + lg) ^ (lr & 7)) * 8]);
        s[ni] = __builtin_amdgcn_mfma_f32_16x16x32_bf16(kb, qa[kd], s[ni], 0, 0, 0);
      }
    }
    __builtin_amdgcn_s_setprio(0);

    float* prow = probs_out + pbase + (size_t)(wid*16 + lr) * SEQ + kt*64;
    unsigned short* psrow = &QP[(wid*16 + lr) * 64];
    #pragma unroll
    for (int ni = 0; ni < 4; ++ni) {
      const f32x4 mv = *reinterpret_cast<const f32x4*>(&Msk[kt*64 + ni*16 + lg*4]);
      f32x4 p;
      p[0] = fexp2(s[ni][0] + mv[0]) * inv_l;
      p[1] = fexp2(s[ni][1] + mv[1]) * inv_l;
      p[2] = fexp2(s[ni][2] + mv[2]) * inv_l;
      p[3] = fexp2(s[ni][3] + mv[3]) * inv_l;
      __builtin_nontemporal_store(p, reinterpret_cast<f32x4*>(prow + ni*16 + lg*4));
      ushort4_t pu;
      pu[0] = bfc(p[0]); pu[1] = bfc(p[1]); pu[2] = bfc(p[2]); pu[3] = bfc(p[3]);
      const int g = (2*ni + (lg >> 1)) ^ (lr & 7);
      *reinterpret_cast<ushort4_t*>(psrow + g*8 + (lg & 1)*4) = pu;
    }

    __builtin_amdgcn_s_setprio(1);
    #pragma unroll
    for (int ks = 0; ks < 2; ++ks) {
      const bf16x8 pb = *reinterpret_cast<const bf16x8*>(
          psrow + ((4*ks + lg) ^ (lr & 7)) * 8);
      #pragma unroll
      for (int nd = 0; nd < 4; ++nd) {
        const int row = nd*16 + lr;   // d
        const bf16x8 vb = *reinterpret_cast<const bf16x8*>(
            &Vs[cur][row * 64 + ((ks*4 + lg) ^ (lr & 7)) * 8]);
        cacc[nd] = __builtin_amdgcn_mfma_f32_16x16x32_bf16(vb, pb, cacc[nd], 0, 0, 0);
      }
    }
    __builtin_amdgcn_s_setprio(0);

    __builtin_amdgcn_sched_barrier(0);
    if (pre) {
      // FIFO: [4 glds kt+1][4 nt probs stores kt] -> retire glds, keep stores
      asm volatile("s_waitcnt vmcnt(4)" ::: "memory");
    }
    __builtin_amdgcn_sched_barrier(0);
    __builtin_amdgcn_s_barrier();
  }

  const int q = qt*64 + wid*16 + lr;
  float* crow = ctx_out + ((size_t)(b * SEQ + q)) * DMODEL + h * HDIM;
  #pragma unroll
  for (int nd = 0; nd < 4; ++nd)
    __builtin_nontemporal_store(cacc[nd], reinterpret_cast<f32x4*>(crow + nd*16 + lg*4));
}

extern "C" void kernel_launch(void* const* d_in, const int* in_sizes, int n_in,
                              void* d_out, int out_size, void* d_ws, size_t ws_size,
                              hipStream_t stream)
{
  const float* X    = (const float*)d_in[0];
  const float* mask = (const float*)d_in[1];
  const float* Wq   = (const float*)d_in[2];
  const float* bq   = (const float*)d_in[3];
  const float* Wk   = (const float*)d_in[4];
  const float* bk   = (const float*)d_in[5];
  const float* Wv   = (const float*)d_in[6];
  const float* bv   = (const float*)d_in[7];

  float* ctx   = (float*)d_out;
  float* probs = ctx + (size_t)NBATCH * SEQ * DMODEL;

  unsigned short* Wt = (unsigned short*)d_ws;                    // [3072][1024] bf16
  unsigned short* Xb = Wt + (size_t)3 * DMODEL * DMODEL;         // [8192][1024] bf16
  unsigned short* Qh = Xb + (size_t)NBATCH * SEQ * DMODEL;       // [B,H,S,D] bf16
  unsigned short* Kh = Qh + (size_t)NBATCH * NHEAD * SEQ * HDIM;
  unsigned short* Vt = Kh + (size_t)NBATCH * NHEAD * SEQ * HDIM; // [B,H,D,S] bf16

  xconv<<<dim3(4096), 256, 0, stream>>>(X, Xb);
  wt_kernel<<<dim3(16, 16, 3), 256, 0, stream>>>(Wq, Wk, Wv, Wt);
  qkv_gemm<<<dim3(64, 24), 256, 0, stream>>>(Xb, Wt, bq, bk, bv, Qh, Kh, Vt);
  attn_kernel<<<dim3(2048), 256, 0, stream>>>(Qh, Kh, Vt, mask, ctx, probs);
}

// Round 13
// 400.843 us; speedup vs baseline: 1.3988x; 1.3988x over previous
//
#include <hip/hip_runtime.h>

#define SEQ    2048
#define DMODEL 1024
#define NHEAD  16
#define HDIM   64
#define NBATCH 4
#define LOG2E  1.44269504088896f

typedef __bf16 bf16x8 __attribute__((ext_vector_type(8)));
typedef float  f32x4  __attribute__((ext_vector_type(4)));
typedef unsigned short ushort8_t __attribute__((ext_vector_type(8)));
typedef unsigned short ushort4_t __attribute__((ext_vector_type(4)));

__device__ __forceinline__ unsigned short bfc(float f) {
  union { __bf16 h; unsigned short u; } v;
  v.h = (__bf16)f;
  return v.u;
}

__device__ __forceinline__ float fexp2(float x) {
#if __has_builtin(__builtin_amdgcn_exp2f)
  return __builtin_amdgcn_exp2f(x);
#else
  return exp2f(x);
#endif
}

// async global->LDS, 16B per lane; LDS dest = wave-uniform base + lane*16
__device__ __forceinline__ void glds16(const void* g, void* l) {
  __builtin_amdgcn_global_load_lds(
      (const __attribute__((address_space(1))) unsigned int*)g,
      (__attribute__((address_space(3))) unsigned int*)l, 16, 0, 0);
}

// ---------------- X fp32 -> bf16 ----------------
__global__ __launch_bounds__(256) void xconv(
    const float* __restrict__ X, unsigned short* __restrict__ Xb)
{
  const size_t i = ((size_t)blockIdx.x * 256 + threadIdx.x) * 8;
  const float4 f0 = *reinterpret_cast<const float4*>(X + i);
  const float4 f1 = *reinterpret_cast<const float4*>(X + i + 4);
  ushort8_t u;
  u[0]=bfc(f0.x); u[1]=bfc(f0.y); u[2]=bfc(f0.z); u[3]=bfc(f0.w);
  u[4]=bfc(f1.x); u[5]=bfc(f1.y); u[6]=bfc(f1.z); u[7]=bfc(f1.w);
  *reinterpret_cast<ushort8_t*>(Xb + i) = u;
}

// ---------------- W transpose: W[k][n] fp32 -> Wt[w*1024+n][k] bf16 ---------
__global__ __launch_bounds__(256) void wt_kernel(
    const float* __restrict__ W0, const float* __restrict__ W1,
    const float* __restrict__ W2, unsigned short* __restrict__ Wt)
{
  const int k0 = blockIdx.x * 64;
  const int n0 = blockIdx.y * 64;
  const int w  = blockIdx.z;
  const float* W = (w == 0) ? W0 : (w == 1) ? W1 : W2;
  const float scale = (w == 0) ? 0.125f * LOG2E : 1.0f;
  unsigned short* dst = Wt + (size_t)w * DMODEL * DMODEL;

  __shared__ __align__(16) unsigned short T[64][72];
  const int t = threadIdx.x;

  #pragma unroll
  for (int i = 0; i < 4; ++i) {
    const int slot = t + i * 256;
    const int row  = slot >> 4;
    const int c4   = (slot & 15) * 4;
    const float4 f = *reinterpret_cast<const float4*>(W + (size_t)(k0 + row) * DMODEL + n0 + c4);
    ushort4_t u;
    u.x = bfc(f.x * scale); u.y = bfc(f.y * scale);
    u.z = bfc(f.z * scale); u.w = bfc(f.w * scale);
    *reinterpret_cast<ushort4_t*>(&T[row][c4]) = u;
  }
  __syncthreads();
  #pragma unroll
  for (int i = 0; i < 2; ++i) {
    const int slot = t + i * 256;
    const int n  = slot >> 3;
    const int k8 = (slot & 7) * 8;
    ushort8_t v;
    #pragma unroll
    for (int j = 0; j < 8; ++j) v[j] = T[k8 + j][n];
    *reinterpret_cast<ushort8_t*>(dst + (size_t)(n0 + n) * DMODEL + k0 + k8) = v;
  }
}

// ---------------- fused QKV GEMM, m97 structure -----------------------------
// w==2 (V) writes TRANSPOSED directly: Vt[bh][d][ss..ss+3] via PLAIN 8B stores
// (L2 write-combines; R12 showed nt sub-line stores amplify writes).
__global__ __launch_bounds__(256) void qkv_gemm(
    const unsigned short* __restrict__ Xb, const unsigned short* __restrict__ Wt,
    const float* __restrict__ bq, const float* __restrict__ bk, const float* __restrict__ bv,
    unsigned short* __restrict__ Qh, unsigned short* __restrict__ Kh, unsigned short* __restrict__ Vt)
{
  const int m0  = blockIdx.x * 128;
  const int n0g = blockIdx.y * 128;
  const int w   = n0g >> 10;
  const float* bias = (w == 0) ? bq : (w == 1) ? bk : bv;
  const float bscale = (w == 0) ? 0.125f * LOG2E : 1.0f;

  __shared__ __align__(16) unsigned short As[128 * 64];
  __shared__ __align__(16) unsigned short Bs[128 * 64];

  const int t = threadIdx.x;
  const int lane = t & 63;
  const int wid  = t >> 6;
  const int wm = wid >> 1, wn = wid & 1;
  const int lr = lane & 15, lg = lane >> 4;

  const f32x4 fz = {0.f, 0.f, 0.f, 0.f};
  f32x4 acc[4][4];
  #pragma unroll
  for (int i = 0; i < 4; ++i)
    #pragma unroll
    for (int j = 0; j < 4; ++j) acc[i][j] = fz;

  const int srow = t >> 3;
  const int sg   = t & 7;

  for (int k0 = 0; k0 < DMODEL; k0 += 64) {
    #pragma unroll
    for (int i = 0; i < 4; ++i) {
      const int row = i * 32 + srow;
      const int gs  = sg ^ (row & 7);
      glds16(Xb + (size_t)(m0 + row) * DMODEL + k0 + gs * 8,
             (void*)(As + row * 64 + sg * 8));
      glds16(Wt + (size_t)(n0g + row) * DMODEL + k0 + gs * 8,
             (void*)(Bs + row * 64 + sg * 8));
    }
    __syncthreads();

    #pragma unroll
    for (int ks = 0; ks < 2; ++ks) {
      bf16x8 a[4], b[4];
      #pragma unroll
      for (int mi = 0; mi < 4; ++mi) {
        const int row = wm * 64 + mi * 16 + lr;
        a[mi] = *reinterpret_cast<const bf16x8*>(As + row * 64 + ((ks * 4 + lg) ^ (row & 7)) * 8);
      }
      #pragma unroll
      for (int ni = 0; ni < 4; ++ni) {
        const int row = wn * 64 + ni * 16 + lr;
        b[ni] = *reinterpret_cast<const bf16x8*>(Bs + row * 64 + ((ks * 4 + lg) ^ (row & 7)) * 8);
      }
      #pragma unroll
      for (int mi = 0; mi < 4; ++mi)
        #pragma unroll
        for (int ni = 0; ni < 4; ++ni)
          acc[mi][ni] = __builtin_amdgcn_mfma_f32_16x16x32_bf16(a[mi], b[ni], acc[mi][ni], 0, 0, 0);
    }
    __syncthreads();
  }

  unsigned short* dst = (w == 0) ? Qh : Kh;
  #pragma unroll
  for (int mi = 0; mi < 4; ++mi) {
    #pragma unroll
    for (int ni = 0; ni < 4; ++ni) {
      const int n = (n0g & 1023) + wn * 64 + ni * 16 + lr;
      const float bn = bias[n] * bscale;
      const int h = n >> 6, d = n & 63;
      const int m = m0 + wm * 64 + mi * 16 + lg * 4;
      const int bb = m >> 11, ss = m & (SEQ - 1);
      if (w == 2) {
        ushort4_t u;
        #pragma unroll
        for (int r = 0; r < 4; ++r) u[r] = bfc(acc[mi][ni][r] + bn);
        *reinterpret_cast<ushort4_t*>(
            Vt + (((size_t)(bb * NHEAD + h)) * HDIM + d) * SEQ + ss) = u;
      } else {
        #pragma unroll
        for (int r = 0; r < 4; ++r)
          dst[(((size_t)(bb * NHEAD + h)) * SEQ + ss + r) * HDIM + d] = bfc(acc[mi][ni][r] + bn);
      }
    }
  }
}

// ---------------- fused attention (R10, unchanged) --------------------------
// 1-D grid 2048, XCD-chunked (T1). Mask row staged to LDS (pre-scaled) so the
// pass-2 vmcnt FIFO is exactly [4 glds][4 nt stores] and the counted vmcnt(4)
// keeps the kt+1 prefetch in flight across the whole tile. probs/ctx nt.
__global__ __launch_bounds__(256) void attn_kernel(
    const unsigned short* __restrict__ Qh, const unsigned short* __restrict__ Kh,
    const unsigned short* __restrict__ Vt, const float* __restrict__ mask,
    float* __restrict__ ctx_out, float* __restrict__ probs_out)
{
  const int bid = blockIdx.x;
  const int L   = (bid & 7) * 256 + (bid >> 3);   // XCD-chunked logical id
  const int qt  = L & 31;
  const int bh  = L >> 5;          // 8 consecutive bh per XCD
  const int h   = bh & (NHEAD - 1);
  const int b   = bh >> 4;

  const int t = threadIdx.x;
  const int lane = t & 63;
  const int wid = t >> 6;
  const int lr = lane & 15, lg = lane >> 4;

  __shared__ __align__(16) unsigned short QP[64 * 64];     // Q staging, then Ps
  __shared__ __align__(16) unsigned short Ks[2][64 * 64];  // linear, XOR-swizzled
  __shared__ __align__(16) unsigned short Vs[2][64 * 64];  // [d][key] swizzled
  __shared__ __align__(16) float Msk[SEQ];                 // mask*log2e

  const size_t qkv_base = (size_t)bh * SEQ * HDIM;
  const size_t vbase    = (size_t)bh * HDIM * SEQ;

  // stage Q tile (64x64) + mask row (pre-scaled)
  {
    const int srow = t >> 3, sc8 = (t & 7) * 8;
    #pragma unroll
    for (int c = 0; c < 2; ++c) {
      const int rr = srow + c * 32;
      *reinterpret_cast<ushort8_t*>(&QP[rr * 64 + sc8]) =
        *reinterpret_cast<const ushort8_t*>(Qh + qkv_base + (size_t)(qt*64 + rr) * HDIM + sc8);
    }
    const float* maskb = mask + b * SEQ;
    #pragma unroll
    for (int i = 0; i < 2; ++i) {
      const int slot = t + i * 256;
      const float4 mv = *reinterpret_cast<const float4*>(maskb + slot * 4);
      f32x4 m4; m4[0]=mv.x*LOG2E; m4[1]=mv.y*LOG2E; m4[2]=mv.z*LOG2E; m4[3]=mv.w*LOG2E;
      *reinterpret_cast<f32x4*>(&Msk[slot * 4]) = m4;
    }
  }
  __syncthreads();

  bf16x8 qa[2];
  qa[0] = *reinterpret_cast<const bf16x8*>(&QP[(wid*16 + lr) * 64 + lg*8]);
  qa[1] = *reinterpret_cast<const bf16x8*>(&QP[(wid*16 + lr) * 64 + 32 + lg*8]);
  __syncthreads();   // all waves hold Q in regs before QP is reused as Ps

  const int krow = t >> 3;
  const int ksg  = t & 7;

  auto stageK = [&](int buf, int kt) {
    #pragma unroll
    for (int i = 0; i < 2; ++i) {
      const int row = i * 32 + krow;
      glds16(Kh + qkv_base + (size_t)(kt*64 + row) * HDIM + ((ksg ^ (row & 7)) * 8),
             (void*)(&Ks[buf][row * 64 + ksg * 8]));
    }
  };
  auto stageV = [&](int buf, int kt) {
    #pragma unroll
    for (int i = 0; i < 2; ++i) {
      const int row = i * 32 + krow;   // d
      glds16(Vt + vbase + (size_t)row * SEQ + kt*64 + ((ksg ^ (row & 7)) * 8),
             (void*)(&Vs[buf][row * 64 + ksg * 8]));
    }
  };

  const f32x4 fz = {0.f, 0.f, 0.f, 0.f};
  float l0 = 0.f, l1 = 0.f;

  // ---- pass 1: S^T = K*Q^T, per-lane exp2 sums ----
  stageK(0, 0);
  asm volatile("s_waitcnt vmcnt(0)" ::: "memory");
  __builtin_amdgcn_sched_barrier(0);
  __builtin_amdgcn_s_barrier();

  for (int kt = 0; kt < SEQ / 64; ++kt) {
    const int cur = kt & 1;
    if (kt < SEQ / 64 - 1) stageK(cur ^ 1, kt + 1);
    __builtin_amdgcn_sched_barrier(0);

    f32x4 s[4];
    #pragma unroll
    for (int ni = 0; ni < 4; ++ni) s[ni] = fz;
    __builtin_amdgcn_s_setprio(1);
    #pragma unroll
    for (int kd = 0; kd < 2; ++kd) {
      #pragma unroll
      for (int ni = 0; ni < 4; ++ni) {
        const int row = ni*16 + lr;
        const bf16x8 kb = *reinterpret_cast<const bf16x8*>(
            &Ks[cur][row * 64 + ((kd*4 + lg) ^ (lr & 7)) * 8]);
        s[ni] = __builtin_amdgcn_mfma_f32_16x16x32_bf16(kb, qa[kd], s[ni], 0, 0, 0);
      }
    }
    __builtin_amdgcn_s_setprio(0);
    #pragma unroll
    for (int ni = 0; ni < 4; ++ni) {
      const f32x4 mv = *reinterpret_cast<const f32x4*>(&Msk[kt*64 + ni*16 + lg*4]);
      l0 += fexp2(s[ni][0] + mv[0]);
      l1 += fexp2(s[ni][1] + mv[1]);
      l0 += fexp2(s[ni][2] + mv[2]);
      l1 += fexp2(s[ni][3] + mv[3]);
    }
    __builtin_amdgcn_sched_barrier(0);
    asm volatile("s_waitcnt vmcnt(0)" ::: "memory");
    __builtin_amdgcn_sched_barrier(0);
    __builtin_amdgcn_s_barrier();
  }

  float l = l0 + l1;
  l += __shfl_xor(l, 16);
  l += __shfl_xor(l, 32);
  const float inv_l = 1.0f / l;

  // ---- pass 2: recompute S^T, write probs (nt), PV (ctx^T = V^T * P^T) ----
  f32x4 cacc[4];
  #pragma unroll
  for (int nd = 0; nd < 4; ++nd) cacc[nd] = fz;

  const size_t pbase = ((size_t)bh * SEQ + qt*64) * SEQ;

  stageK(0, 0); stageV(0, 0);
  asm volatile("s_waitcnt vmcnt(0)" ::: "memory");
  __builtin_amdgcn_sched_barrier(0);
  __builtin_amdgcn_s_barrier();

  for (int kt = 0; kt < SEQ / 64; ++kt) {
    const int cur = kt & 1;
    const bool pre = (kt < SEQ / 64 - 1);
    if (pre) { stageK(cur ^ 1, kt + 1); stageV(cur ^ 1, kt + 1); }
    __builtin_amdgcn_sched_barrier(0);

    f32x4 s[4];
    #pragma unroll
    for (int ni = 0; ni < 4; ++ni) s[ni] = fz;
    __builtin_amdgcn_s_setprio(1);
    #pragma unroll
    for (int kd = 0; kd < 2; ++kd) {
      #pragma unroll
      for (int ni = 0; ni < 4; ++ni) {
        const int row = ni*16 + lr;
        const bf16x8 kb = *reinterpret_cast<const bf16x8*>(
            &Ks[cur][row * 64 + ((kd*4 + lg) ^ (lr & 7)) * 8]);
        s[ni] = __builtin_amdgcn_mfma_f32_16x16x32_bf16(kb, qa[kd], s[ni], 0, 0, 0);
      }
    }
    __builtin_amdgcn_s_setprio(0);

    float* prow = probs_out + pbase + (size_t)(wid*16 + lr) * SEQ + kt*64;
    unsigned short* psrow = &QP[(wid*16 + lr) * 64];
    #pragma unroll
    for (int ni = 0; ni < 4; ++ni) {
      const f32x4 mv = *reinterpret_cast<const f32x4*>(&Msk[kt*64 + ni*16 + lg*4]);
      f32x4 p;
      p[0] = fexp2(s[ni][0] + mv[0]) * inv_l;
      p[1] = fexp2(s[ni][1] + mv[1]) * inv_l;
      p[2] = fexp2(s[ni][2] + mv[2]) * inv_l;
      p[3] = fexp2(s[ni][3] + mv[3]) * inv_l;
      __builtin_nontemporal_store(p, reinterpret_cast<f32x4*>(prow + ni*16 + lg*4));
      ushort4_t pu;
      pu[0] = bfc(p[0]); pu[1] = bfc(p[1]); pu[2] = bfc(p[2]); pu[3] = bfc(p[3]);
      const int g = (2*ni + (lg >> 1)) ^ (lr & 7);
      *reinterpret_cast<ushort4_t*>(psrow + g*8 + (lg & 1)*4) = pu;
    }

    __builtin_amdgcn_s_setprio(1);
    #pragma unroll
    for (int ks = 0; ks < 2; ++ks) {
      const bf16x8 pb = *reinterpret_cast<const bf16x8*>(
          psrow + ((4*ks + lg) ^ (lr & 7)) * 8);
      #pragma unroll
      for (int nd = 0; nd < 4; ++nd) {
        const int row = nd*16 + lr;   // d
        const bf16x8 vb = *reinterpret_cast<const bf16x8*>(
            &Vs[cur][row * 64 + ((ks*4 + lg) ^ (lr & 7)) * 8]);
        cacc[nd] = __builtin_amdgcn_mfma_f32_16x16x32_bf16(vb, pb, cacc[nd], 0, 0, 0);
      }
    }
    __builtin_amdgcn_s_setprio(0);

    __builtin_amdgcn_sched_barrier(0);
    if (pre) {
      // FIFO: [4 glds kt+1][4 nt probs stores kt] -> retire glds, keep stores
      asm volatile("s_waitcnt vmcnt(4)" ::: "memory");
    }
    __builtin_amdgcn_sched_barrier(0);
    __builtin_amdgcn_s_barrier();
  }

  const int q = qt*64 + wid*16 + lr;
  float* crow = ctx_out + ((size_t)(b * SEQ + q)) * DMODEL + h * HDIM;
  #pragma unroll
  for (int nd = 0; nd < 4; ++nd)
    __builtin_nontemporal_store(cacc[nd], reinterpret_cast<f32x4*>(crow + nd*16 + lg*4));
}

extern "C" void kernel_launch(void* const* d_in, const int* in_sizes, int n_in,
                              void* d_out, int out_size, void* d_ws, size_t ws_size,
                              hipStream_t stream)
{
  const float* X    = (const float*)d_in[0];
  const float* mask = (const float*)d_in[1];
  const float* Wq   = (const float*)d_in[2];
  const float* bq   = (const float*)d_in[3];
  const float* Wk   = (const float*)d_in[4];
  const float* bk   = (const float*)d_in[5];
  const float* Wv   = (const float*)d_in[6];
  const float* bv   = (const float*)d_in[7];

  float* ctx   = (float*)d_out;
  float* probs = ctx + (size_t)NBATCH * SEQ * DMODEL;

  unsigned short* Wt = (unsigned short*)d_ws;                    // [3072][1024] bf16
  unsigned short* Xb = Wt + (size_t)3 * DMODEL * DMODEL;         // [8192][1024] bf16
  unsigned short* Qh = Xb + (size_t)NBATCH * SEQ * DMODEL;       // [B,H,S,D] bf16
  unsigned short* Kh = Qh + (size_t)NBATCH * NHEAD * SEQ * HDIM;
  unsigned short* Vt = Kh + (size_t)NBATCH * NHEAD * SEQ * HDIM; // [B,H,D,S] bf16

  xconv<<<dim3(4096), 256, 0, stream>>>(X, Xb);
  wt_kernel<<<dim3(16, 16, 3), 256, 0, stream>>>(Wq, Wk, Wv, Wt);
  qkv_gemm<<<dim3(64, 24), 256, 0, stream>>>(Xb, Wt, bq, bk, bv, Qh, Kh, Vt);
  attn_kernel<<<dim3(2048), 256, 0, stream>>>(Qh, Kh, Vt, mask, ctx, probs);
}

// Round 14
// 394.161 us; speedup vs baseline: 1.4226x; 1.0170x over previous
//
#include <hip/hip_runtime.h>

#define SEQ    2048
#define DMODEL 1024
#define NHEAD  16
#define HDIM   64
#define NBATCH 4
#define LOG2E  1.44269504088896f

typedef __bf16 bf16x8 __attribute__((ext_vector_type(8)));
typedef float  f32x4  __attribute__((ext_vector_type(4)));
typedef unsigned short ushort8_t __attribute__((ext_vector_type(8)));
typedef unsigned short ushort4_t __attribute__((ext_vector_type(4)));

__device__ __forceinline__ unsigned short bfc(float f) {
  union { __bf16 h; unsigned short u; } v;
  v.h = (__bf16)f;
  return v.u;
}

__device__ __forceinline__ float fexp2(float x) {
#if __has_builtin(__builtin_amdgcn_exp2f)
  return __builtin_amdgcn_exp2f(x);
#else
  return exp2f(x);
#endif
}

// async global->LDS, 16B per lane; LDS dest = wave-uniform base + lane*16
__device__ __forceinline__ void glds16(const void* g, void* l) {
  __builtin_amdgcn_global_load_lds(
      (const __attribute__((address_space(1))) unsigned int*)g,
      (__attribute__((address_space(3))) unsigned int*)l, 16, 0, 0);
}

// ---------------- X fp32 -> bf16 ----------------
__global__ __launch_bounds__(256) void xconv(
    const float* __restrict__ X, unsigned short* __restrict__ Xb)
{
  const size_t i = ((size_t)blockIdx.x * 256 + threadIdx.x) * 8;
  const float4 f0 = *reinterpret_cast<const float4*>(X + i);
  const float4 f1 = *reinterpret_cast<const float4*>(X + i + 4);
  ushort8_t u;
  u[0]=bfc(f0.x); u[1]=bfc(f0.y); u[2]=bfc(f0.z); u[3]=bfc(f0.w);
  u[4]=bfc(f1.x); u[5]=bfc(f1.y); u[6]=bfc(f1.z); u[7]=bfc(f1.w);
  *reinterpret_cast<ushort8_t*>(Xb + i) = u;
}

// ---------------- W transpose: W[k][n] fp32 -> Wt[w*1024+n][k] bf16 ---------
__global__ __launch_bounds__(256) void wt_kernel(
    const float* __restrict__ W0, const float* __restrict__ W1,
    const float* __restrict__ W2, unsigned short* __restrict__ Wt)
{
  const int k0 = blockIdx.x * 64;
  const int n0 = blockIdx.y * 64;
  const int w  = blockIdx.z;
  const float* W = (w == 0) ? W0 : (w == 1) ? W1 : W2;
  const float scale = (w == 0) ? 0.125f * LOG2E : 1.0f;
  unsigned short* dst = Wt + (size_t)w * DMODEL * DMODEL;

  __shared__ __align__(16) unsigned short T[64][72];
  const int t = threadIdx.x;

  #pragma unroll
  for (int i = 0; i < 4; ++i) {
    const int slot = t + i * 256;
    const int row  = slot >> 4;
    const int c4   = (slot & 15) * 4;
    const float4 f = *reinterpret_cast<const float4*>(W + (size_t)(k0 + row) * DMODEL + n0 + c4);
    ushort4_t u;
    u.x = bfc(f.x * scale); u.y = bfc(f.y * scale);
    u.z = bfc(f.z * scale); u.w = bfc(f.w * scale);
    *reinterpret_cast<ushort4_t*>(&T[row][c4]) = u;
  }
  __syncthreads();
  #pragma unroll
  for (int i = 0; i < 2; ++i) {
    const int slot = t + i * 256;
    const int n  = slot >> 3;
    const int k8 = (slot & 7) * 8;
    ushort8_t v;
    #pragma unroll
    for (int j = 0; j < 8; ++j) v[j] = T[k8 + j][n];
    *reinterpret_cast<ushort8_t*>(dst + (size_t)(n0 + n) * DMODEL + k0 + k8) = v;
  }
}

// ---------------- fused QKV GEMM (R13: fused transposed-V epilogue) ---------
__global__ __launch_bounds__(256) void qkv_gemm(
    const unsigned short* __restrict__ Xb, const unsigned short* __restrict__ Wt,
    const float* __restrict__ bq, const float* __restrict__ bk, const float* __restrict__ bv,
    unsigned short* __restrict__ Qh, unsigned short* __restrict__ Kh, unsigned short* __restrict__ Vt)
{
  const int m0  = blockIdx.x * 128;
  const int n0g = blockIdx.y * 128;
  const int w   = n0g >> 10;
  const float* bias = (w == 0) ? bq : (w == 1) ? bk : bv;
  const float bscale = (w == 0) ? 0.125f * LOG2E : 1.0f;

  __shared__ __align__(16) unsigned short As[128 * 64];
  __shared__ __align__(16) unsigned short Bs[128 * 64];

  const int t = threadIdx.x;
  const int lane = t & 63;
  const int wid  = t >> 6;
  const int wm = wid >> 1, wn = wid & 1;
  const int lr = lane & 15, lg = lane >> 4;

  const f32x4 fz = {0.f, 0.f, 0.f, 0.f};
  f32x4 acc[4][4];
  #pragma unroll
  for (int i = 0; i < 4; ++i)
    #pragma unroll
    for (int j = 0; j < 4; ++j) acc[i][j] = fz;

  const int srow = t >> 3;
  const int sg   = t & 7;

  for (int k0 = 0; k0 < DMODEL; k0 += 64) {
    #pragma unroll
    for (int i = 0; i < 4; ++i) {
      const int row = i * 32 + srow;
      const int gs  = sg ^ (row & 7);
      glds16(Xb + (size_t)(m0 + row) * DMODEL + k0 + gs * 8,
             (void*)(As + row * 64 + sg * 8));
      glds16(Wt + (size_t)(n0g + row) * DMODEL + k0 + gs * 8,
             (void*)(Bs + row * 64 + sg * 8));
    }
    __syncthreads();

    #pragma unroll
    for (int ks = 0; ks < 2; ++ks) {
      bf16x8 a[4], b[4];
      #pragma unroll
      for (int mi = 0; mi < 4; ++mi) {
        const int row = wm * 64 + mi * 16 + lr;
        a[mi] = *reinterpret_cast<const bf16x8*>(As + row * 64 + ((ks * 4 + lg) ^ (row & 7)) * 8);
      }
      #pragma unroll
      for (int ni = 0; ni < 4; ++ni) {
        const int row = wn * 64 + ni * 16 + lr;
        b[ni] = *reinterpret_cast<const bf16x8*>(Bs + row * 64 + ((ks * 4 + lg) ^ (row & 7)) * 8);
      }
      #pragma unroll
      for (int mi = 0; mi < 4; ++mi)
        #pragma unroll
        for (int ni = 0; ni < 4; ++ni)
          acc[mi][ni] = __builtin_amdgcn_mfma_f32_16x16x32_bf16(a[mi], b[ni], acc[mi][ni], 0, 0, 0);
    }
    __syncthreads();
  }

  unsigned short* dst = (w == 0) ? Qh : Kh;
  #pragma unroll
  for (int mi = 0; mi < 4; ++mi) {
    #pragma unroll
    for (int ni = 0; ni < 4; ++ni) {
      const int n = (n0g & 1023) + wn * 64 + ni * 16 + lr;
      const float bn = bias[n] * bscale;
      const int h = n >> 6, d = n & 63;
      const int m = m0 + wm * 64 + mi * 16 + lg * 4;
      const int bb = m >> 11, ss = m & (SEQ - 1);
      if (w == 2) {
        ushort4_t u;
        #pragma unroll
        for (int r = 0; r < 4; ++r) u[r] = bfc(acc[mi][ni][r] + bn);
        *reinterpret_cast<ushort4_t*>(
            Vt + (((size_t)(bb * NHEAD + h)) * HDIM + d) * SEQ + ss) = u;
      } else {
        #pragma unroll
        for (int r = 0; r < 4; ++r)
          dst[(((size_t)(bb * NHEAD + h)) * SEQ + ss + r) * HDIM + d] = bfc(acc[mi][ni][r] + bn);
      }
    }
  }
}

// ---------------- fused attention ----------------
// R13 base; pass 1 now consumes 128 k-rows per barrier-pair (16 iters not 32)
// with the big K buffer UNION-aliased over pass 2's Ks/Vs so LDS stays 48KB
// (3 blocks/CU). Pass 2 unchanged: LDS mask, counted vmcnt(4), nt stores.
__global__ __launch_bounds__(256) void attn_kernel(
    const unsigned short* __restrict__ Qh, const unsigned short* __restrict__ Kh,
    const unsigned short* __restrict__ Vt, const float* __restrict__ mask,
    float* __restrict__ ctx_out, float* __restrict__ probs_out)
{
  const int bid = blockIdx.x;
  const int L   = (bid & 7) * 256 + (bid >> 3);   // XCD-chunked logical id
  const int qt  = L & 31;
  const int bh  = L >> 5;          // 8 consecutive bh per XCD
  const int h   = bh & (NHEAD - 1);
  const int b   = bh >> 4;

  const int t = threadIdx.x;
  const int lane = t & 63;
  const int wid = t >> 6;
  const int lr = lane & 15, lg = lane >> 4;

  __shared__ __align__(16) unsigned short QP[64 * 64];     // Q staging, then Ps
  // union buffer: pass1 = [buf][128 rows of K]; pass2 = [buf][K(64) | V(64)]
  __shared__ __align__(16) unsigned short KV[2][2][64 * 64];
  __shared__ __align__(16) float Msk[SEQ];                 // mask*log2e

  const size_t qkv_base = (size_t)bh * SEQ * HDIM;
  const size_t vbase    = (size_t)bh * HDIM * SEQ;

  // stage Q tile (64x64) + mask row (pre-scaled)
  {
    const int srow = t >> 3, sc8 = (t & 7) * 8;
    #pragma unroll
    for (int c = 0; c < 2; ++c) {
      const int rr = srow + c * 32;
      *reinterpret_cast<ushort8_t*>(&QP[rr * 64 + sc8]) =
        *reinterpret_cast<const ushort8_t*>(Qh + qkv_base + (size_t)(qt*64 + rr) * HDIM + sc8);
    }
    const float* maskb = mask + b * SEQ;
    #pragma unroll
    for (int i = 0; i < 2; ++i) {
      const int slot = t + i * 256;
      const float4 mv = *reinterpret_cast<const float4*>(maskb + slot * 4);
      f32x4 m4; m4[0]=mv.x*LOG2E; m4[1]=mv.y*LOG2E; m4[2]=mv.z*LOG2E; m4[3]=mv.w*LOG2E;
      *reinterpret_cast<f32x4*>(&Msk[slot * 4]) = m4;
    }
  }
  __syncthreads();

  bf16x8 qa[2];
  qa[0] = *reinterpret_cast<const bf16x8*>(&QP[(wid*16 + lr) * 64 + lg*8]);
  qa[1] = *reinterpret_cast<const bf16x8*>(&QP[(wid*16 + lr) * 64 + 32 + lg*8]);
  __syncthreads();   // all waves hold Q in regs before QP is reused as Ps

  const int krow = t >> 3;   // 0..31
  const int ksg  = t & 7;

  // pass-1 staging: 128 k-rows per call into KV[buf][0..1]
  auto stageK2 = [&](int buf, int kt2) {
    #pragma unroll
    for (int i = 0; i < 4; ++i) {
      const int row = i * 32 + krow;   // 0..127; half uniform per (wave,i)
      glds16(Kh + qkv_base + (size_t)(kt2*128 + row) * HDIM + ((ksg ^ (row & 7)) * 8),
             (void*)(&KV[buf][row >> 6][(row & 63) * 64 + ksg * 8]));
    }
  };
  // pass-2 staging: 64 rows of K into KV[buf][0], 64 d-rows of V into KV[buf][1]
  auto stageK = [&](int buf, int kt) {
    #pragma unroll
    for (int i = 0; i < 2; ++i) {
      const int row = i * 32 + krow;
      glds16(Kh + qkv_base + (size_t)(kt*64 + row) * HDIM + ((ksg ^ (row & 7)) * 8),
             (void*)(&KV[buf][0][row * 64 + ksg * 8]));
    }
  };
  auto stageV = [&](int buf, int kt) {
    #pragma unroll
    for (int i = 0; i < 2; ++i) {
      const int row = i * 32 + krow;   // d
      glds16(Vt + vbase + (size_t)row * SEQ + kt*64 + ((ksg ^ (row & 7)) * 8),
             (void*)(&KV[buf][1][row * 64 + ksg * 8]));
    }
  };

  const f32x4 fz = {0.f, 0.f, 0.f, 0.f};
  float l0 = 0.f, l1 = 0.f;

  // ---- pass 1: S^T = K*Q^T over 128-row double tiles, per-lane exp2 sums ----
  stageK2(0, 0);
  asm volatile("s_waitcnt vmcnt(0)" ::: "memory");
  __builtin_amdgcn_sched_barrier(0);
  __builtin_amdgcn_s_barrier();

  for (int kt2 = 0; kt2 < SEQ / 128; ++kt2) {
    const int cur = kt2 & 1;
    if (kt2 < SEQ / 128 - 1) stageK2(cur ^ 1, kt2 + 1);
    __builtin_amdgcn_sched_barrier(0);

    #pragma unroll
    for (int sub = 0; sub < 2; ++sub) {
      f32x4 s[4];
      #pragma unroll
      for (int ni = 0; ni < 4; ++ni) s[ni] = fz;
      __builtin_amdgcn_s_setprio(1);
      #pragma unroll
      for (int kd = 0; kd < 2; ++kd) {
        #pragma unroll
        for (int ni = 0; ni < 4; ++ni) {
          const int row = ni*16 + lr;
          const bf16x8 kb = *reinterpret_cast<const bf16x8*>(
              &KV[cur][sub][row * 64 + ((kd*4 + lg) ^ (lr & 7)) * 8]);
          s[ni] = __builtin_amdgcn_mfma_f32_16x16x32_bf16(kb, qa[kd], s[ni], 0, 0, 0);
        }
      }
      __builtin_amdgcn_s_setprio(0);
      #pragma unroll
      for (int ni = 0; ni < 4; ++ni) {
        const f32x4 mv = *reinterpret_cast<const f32x4*>(
            &Msk[kt2*128 + sub*64 + ni*16 + lg*4]);
        l0 += fexp2(s[ni][0] + mv[0]);
        l1 += fexp2(s[ni][1] + mv[1]);
        l0 += fexp2(s[ni][2] + mv[2]);
        l1 += fexp2(s[ni][3] + mv[3]);
      }
    }
    __builtin_amdgcn_sched_barrier(0);
    asm volatile("s_waitcnt vmcnt(0)" ::: "memory");
    __builtin_amdgcn_sched_barrier(0);
    __builtin_amdgcn_s_barrier();
  }

  float l = l0 + l1;
  l += __shfl_xor(l, 16);
  l += __shfl_xor(l, 32);
  const float inv_l = 1.0f / l;

  // ---- pass 2: recompute S^T, write probs (nt), PV (ctx^T = V^T * P^T) ----
  f32x4 cacc[4];
  #pragma unroll
  for (int nd = 0; nd < 4; ++nd) cacc[nd] = fz;

  const size_t pbase = ((size_t)bh * SEQ + qt*64) * SEQ;

  stageK(0, 0); stageV(0, 0);
  asm volatile("s_waitcnt vmcnt(0)" ::: "memory");
  __builtin_amdgcn_sched_barrier(0);
  __builtin_amdgcn_s_barrier();

  for (int kt = 0; kt < SEQ / 64; ++kt) {
    const int cur = kt & 1;
    const bool pre = (kt < SEQ / 64 - 1);
    if (pre) { stageK(cur ^ 1, kt + 1); stageV(cur ^ 1, kt + 1); }
    __builtin_amdgcn_sched_barrier(0);

    f32x4 s[4];
    #pragma unroll
    for (int ni = 0; ni < 4; ++ni) s[ni] = fz;
    __builtin_amdgcn_s_setprio(1);
    #pragma unroll
    for (int kd = 0; kd < 2; ++kd) {
      #pragma unroll
      for (int ni = 0; ni < 4; ++ni) {
        const int row = ni*16 + lr;
        const bf16x8 kb = *reinterpret_cast<const bf16x8*>(
            &KV[cur][0][row * 64 + ((kd*4 + lg) ^ (lr & 7)) * 8]);
        s[ni] = __builtin_amdgcn_mfma_f32_16x16x32_bf16(kb, qa[kd], s[ni], 0, 0, 0);
      }
    }
    __builtin_amdgcn_s_setprio(0);

    float* prow = probs_out + pbase + (size_t)(wid*16 + lr) * SEQ + kt*64;
    unsigned short* psrow = &QP[(wid*16 + lr) * 64];
    #pragma unroll
    for (int ni = 0; ni < 4; ++ni) {
      const f32x4 mv = *reinterpret_cast<const f32x4*>(&Msk[kt*64 + ni*16 + lg*4]);
      f32x4 p;
      p[0] = fexp2(s[ni][0] + mv[0]) * inv_l;
      p[1] = fexp2(s[ni][1] + mv[1]) * inv_l;
      p[2] = fexp2(s[ni][2] + mv[2]) * inv_l;
      p[3] = fexp2(s[ni][3] + mv[3]) * inv_l;
      __builtin_nontemporal_store(p, reinterpret_cast<f32x4*>(prow + ni*16 + lg*4));
      ushort4_t pu;
      pu[0] = bfc(p[0]); pu[1] = bfc(p[1]); pu[2] = bfc(p[2]); pu[3] = bfc(p[3]);
      const int g = (2*ni + (lg >> 1)) ^ (lr & 7);
      *reinterpret_cast<ushort4_t*>(psrow + g*8 + (lg & 1)*4) = pu;
    }

    __builtin_amdgcn_s_setprio(1);
    #pragma unroll
    for (int ks = 0; ks < 2; ++ks) {
      const bf16x8 pb = *reinterpret_cast<const bf16x8*>(
          psrow + ((4*ks + lg) ^ (lr & 7)) * 8);
      #pragma unroll
      for (int nd = 0; nd < 4; ++nd) {
        const int row = nd*16 + lr;   // d
        const bf16x8 vb = *reinterpret_cast<const bf16x8*>(
            &KV[cur][1][row * 64 + ((ks*4 + lg) ^ (lr & 7)) * 8]);
        cacc[nd] = __builtin_amdgcn_mfma_f32_16x16x32_bf16(vb, pb, cacc[nd], 0, 0, 0);
      }
    }
    __builtin_amdgcn_s_setprio(0);

    __builtin_amdgcn_sched_barrier(0);
    if (pre) {
      // FIFO: [4 glds kt+1][4 nt probs stores kt] -> retire glds, keep stores
      asm volatile("s_waitcnt vmcnt(4)" ::: "memory");
    }
    __builtin_amdgcn_sched_barrier(0);
    __builtin_amdgcn_s_barrier();
  }

  const int q = qt*64 + wid*16 + lr;
  float* crow = ctx_out + ((size_t)(b * SEQ + q)) * DMODEL + h * HDIM;
  #pragma unroll
  for (int nd = 0; nd < 4; ++nd)
    __builtin_nontemporal_store(cacc[nd], reinterpret_cast<f32x4*>(crow + nd*16 + lg*4));
}

extern "C" void kernel_launch(void* const* d_in, const int* in_sizes, int n_in,
                              void* d_out, int out_size, void* d_ws, size_t ws_size,
                              hipStream_t stream)
{
  const float* X    = (const float*)d_in[0];
  const float* mask = (const float*)d_in[1];
  const float* Wq   = (const float*)d_in[2];
  const float* bq   = (const float*)d_in[3];
  const float* Wk   = (const float*)d_in[4];
  const float* bk   = (const float*)d_in[5];
  const float* Wv   = (const float*)d_in[6];
  const float* bv   = (const float*)d_in[7];

  float* ctx   = (float*)d_out;
  float* probs = ctx + (size_t)NBATCH * SEQ * DMODEL;

  unsigned short* Wt = (unsigned short*)d_ws;                    // [3072][1024] bf16
  unsigned short* Xb = Wt + (size_t)3 * DMODEL * DMODEL;         // [8192][1024] bf16
  unsigned short* Qh = Xb + (size_t)NBATCH * SEQ * DMODEL;       // [B,H,S,D] bf16
  unsigned short* Kh = Qh + (size_t)NBATCH * NHEAD * SEQ * HDIM;
  unsigned short* Vt = Kh + (size_t)NBATCH * NHEAD * SEQ * HDIM; // [B,H,D,S] bf16

  xconv<<<dim3(4096), 256, 0, stream>>>(X, Xb);
  wt_kernel<<<dim3(16, 16, 3), 256, 0, stream>>>(Wq, Wk, Wv, Wt);
  qkv_gemm<<<dim3(64, 24), 256, 0, stream>>>(Xb, Wt, bq, bk, bv, Qh, Kh, Vt);
  attn_kernel<<<dim3(2048), 256, 0, stream>>>(Qh, Kh, Vt, mask, ctx, probs);
}